// Round 17
// baseline (164.970 us; speedup 1.0000x reference)
//
#include <hip/hip_runtime.h>
#include <hip/hip_bf16.h>

#define C 32
#define R 8
#define NPB 32        // nodes per block in nodeZ part
#define K_ELL 32      // ELL slots per row
#define OVF_CAP 65536
#define NBKT 8        // XCD buckets

typedef unsigned int u32;
__device__ __forceinline__ float bflo(u32 u) { return __uint_as_float(u << 16); }
__device__ __forceinline__ float bfhi(u32 u) { return __uint_as_float(u & 0xffff0000u); }
__device__ __forceinline__ u32 f2bf_bits(float f) {
    u32 u = __float_as_uint(f);
    u32 lsb = (u >> 16) & 1u;
    return (u + 0x7fffu + lsb) >> 16;
}

// ---- M[r][c][j] = sum_o W_tp[c][r][o] * W1[r*C+o][j]   (f32, 32 KB) ----
__global__ void k_prepM(const float* __restrict__ Wtp, const float* __restrict__ W1,
                        float* __restrict__ M) {
    int idx = blockIdx.x * 256 + threadIdx.x;
    if (idx >= R * C * C) return;
    int r = idx >> 10;
    int c = (idx >> 5) & 31;
    int j = idx & 31;
    float acc = 0.f;
#pragma unroll
    for (int o = 0; o < C; ++o)
        acc = fmaf(Wtp[c * R * C + r * C + o], W1[(r * C + o) * C + j], acc);
    M[idx] = acc;
}

// ---- fused: blocks [0,ZB): nodeZ | blocks [ZB,..): edge binning into 8 buckets ----
// Bucket k holds edges whose row is in [k*RPB8,(k+1)*RPB8): records {row|col<<16, dist}
// written COALESCED (LDS staging + one global-atomic base per bucket per block).
__global__ void k_fused(const float* __restrict__ x, const float* __restrict__ M,
                        __hip_bfloat16* __restrict__ z,
                        const int* __restrict__ ei, const float* __restrict__ pos,
                        int* __restrict__ cnt, int* __restrict__ ovfcnt,
                        int* __restrict__ gbcnt, uint4* __restrict__ ovf,
                        uint2* __restrict__ bucket, u32* __restrict__ ell,
                        int N, int E, int ZB, int RPB8, int CAP) {
    __shared__ float xs[NPB * C];
    __shared__ u32 s_rc[NBKT * 256];
    __shared__ u32 s_d[NBKT * 256];
    __shared__ int lcnt[NBKT], lbase[NBKT];
    int t = threadIdx.x;
    if ((int)blockIdx.x < ZB) {
        int n0 = blockIdx.x * NPB;
        for (int i = t * 4; i < NPB * C; i += 256 * 4) {
            size_t gbase = (size_t)n0 * C + i;
            float4 v = make_float4(0.f, 0.f, 0.f, 0.f);
            if (gbase + 3 < (size_t)N * C) v = *(const float4*)(x + gbase);
            *(float4*)(xs + i) = v;
        }
        __syncthreads();
        int r = t & 7, j = t >> 3;
        float m[C];
#pragma unroll
        for (int c = 0; c < C; ++c) m[c] = M[r * C * C + c * C + j];
        int nmax = N - n0; if (nmax > NPB) nmax = NPB;
        for (int nn = 0; nn < nmax; ++nn) {
            const float* xp = xs + nn * C;
            float acc = 0.f;
#pragma unroll
            for (int c = 0; c < C; ++c) acc = fmaf(xp[c], m[c], acc);
            z[(size_t)(n0 + nn) * (R * C) + t] = __float2bfloat16(acc);
        }
    } else {
        if (t < NBKT) lcnt[t] = 0;
        __syncthreads();
        int i = (blockIdx.x - ZB) * 256 + t;
        if (i < E) {
            int r = ei[i];
            int c = ei[E + i];
            r = ((unsigned)r < (unsigned)N) ? r : 0;
            c = ((unsigned)c < (unsigned)N) ? c : 0;
            float dx = pos[r * 3 + 0] - pos[c * 3 + 0];
            float dy = pos[r * 3 + 1] - pos[c * 3 + 1];
            float dz = pos[r * 3 + 2] - pos[c * 3 + 2];
            float dist = sqrtf(fmaf(dx, dx, fmaf(dy, dy, dz * dz)) + 1e-12f);
            int k = r / RPB8;
            int slot = atomicAdd(&lcnt[k], 1);
            s_rc[k * 256 + slot] = (u32)r | ((u32)c << 16);
            s_d[k * 256 + slot]  = __float_as_uint(dist);
        }
        __syncthreads();
        if (t < NBKT) lbase[t] = atomicAdd(&gbcnt[t], lcnt[t]);
        __syncthreads();
        for (int kk = 0; kk < NBKT; ++kk) {
            int ck = lcnt[kk];
            if (t < ck) {
                int p = lbase[kk] + t;
                u32 rcv = s_rc[kk * 256 + t];
                u32 db  = s_d[kk * 256 + t];
                if (p < CAP) {
                    uint2 rec; rec.x = rcv; rec.y = db;
                    bucket[(size_t)kk * CAP + p] = rec;
                } else {
                    // capacity fallback (statistically ~impossible): direct scatter
                    int r = rcv & 0xffff, c = (int)(rcv >> 16);
                    float dist = __uint_as_float(db);
                    int local = atomicAdd(&cnt[r], 1);
                    if (local < K_ELL)
                        ell[(size_t)r * K_ELL + local] = (u32)c | (f2bf_bits(dist) << 16);
                    else {
                        int q = atomicAdd(ovfcnt, 1);
                        if (q < OVF_CAP) ovf[q] = make_uint4((u32)r, (u32)c, db, 0u);
                    }
                }
            }
        }
    }
}

// ---- phase 2: XCD-local scatter. block b -> bucket b&7 (round-robin XCD match) ----
__global__ void k_scatter2(const uint2* __restrict__ bucket, const int* __restrict__ gbcnt,
                           int* __restrict__ cnt, int* __restrict__ ovfcnt,
                           uint4* __restrict__ ovf, u32* __restrict__ ell, int CAP) {
    int k = blockIdx.x & (NBKT - 1);
    int idx = (int)(blockIdx.x >> 3) * 256 + threadIdx.x;
    int cn = gbcnt[k]; if (cn > CAP) cn = CAP;
    if (idx >= cn) return;
    uint2 rec = bucket[(size_t)k * CAP + idx];
    int r = rec.x & 0xffff, c = (int)(rec.x >> 16);
    float dist = __uint_as_float(rec.y);
    int local = atomicAdd(&cnt[r], 1);
    if (local < K_ELL) {
        ell[(size_t)r * K_ELL + local] = (u32)c | (f2bf_bits(dist) << 16);
    } else {
        int q = atomicAdd(ovfcnt, 1);
        if (q < OVF_CAP) ovf[q] = make_uint4((u32)r, (u32)c, rec.y, 0u);
    }
}

__device__ __forceinline__ float silu_f(float h) {
    return h * __builtin_amdgcn_rcpf(1.f + __expf(-h));
}

// per-lane full-rbf dot: h = b1j + sum_r rbf(d,r)*z_r  — 2 exps, no shuffles.
__device__ __forceinline__ float rbf_dot(float d, uint4 zv, float b1j) {
    const float Einv = 0.36787944f;   // e^-1
    float u = 1.3999999f * d;
    float f = 0.3989423f * __expf(-0.5f * u * u);
    float t = __expf(u - 0.5f);
    float h = fmaf(f, bflo(zv.x), b1j);
    f *= t;            h = fmaf(f, bfhi(zv.x), h);
    t *= Einv; f *= t; h = fmaf(f, bflo(zv.y), h);
    t *= Einv; f *= t; h = fmaf(f, bfhi(zv.y), h);
    t *= Einv; f *= t; h = fmaf(f, bflo(zv.z), h);
    t *= Einv; f *= t; h = fmaf(f, bfhi(zv.z), h);
    t *= Einv; f *= t; h = fmaf(f, bflo(zv.w), h);
    t *= Einv; f *= t; h = fmaf(f, bfhi(zv.w), h);
    return h;
}

// ---- per-row ELL edge kernel: 32 lanes = one row; fused W2/b2 epilogue ----
__global__ void k_edge_ell(const int* __restrict__ cnt, const u32* __restrict__ ell,
                           const __hip_bfloat16* __restrict__ z,
                           const float* __restrict__ x, const float* __restrict__ b1,
                           const float* __restrict__ W2, const float* __restrict__ b2,
                           float* __restrict__ out, int N) {
    __shared__ float W2s[C * C];
    for (int i = threadIdx.x; i < C * C; i += blockDim.x) W2s[i] = W2[i];
    __syncthreads();
    int gt = blockIdx.x * blockDim.x + threadIdx.x;
    int j = gt & 31;
    int n = gt >> 5;
    if (n >= N) return;
    int deg = cnt[n];
    int m = deg < K_ELL ? deg : K_ELL;
    u32 packv = 0u;
    if (j < m) packv = ell[(size_t)n * K_ELL + j];
    float b1j = b1[j];
    float acc = 0.f;
    int base = 0;
    for (; base + 4 <= m; base += 4) {
        u32 w0 = __shfl(packv, base + 0, 32);
        u32 w1 = __shfl(packv, base + 1, 32);
        u32 w2 = __shfl(packv, base + 2, 32);
        u32 w3 = __shfl(packv, base + 3, 32);
        uint4 z0 = ((const uint4*)(z + (size_t)(w0 & 0xffffu) * (R * C)))[j];
        uint4 z1 = ((const uint4*)(z + (size_t)(w1 & 0xffffu) * (R * C)))[j];
        uint4 z2 = ((const uint4*)(z + (size_t)(w2 & 0xffffu) * (R * C)))[j];
        uint4 z3 = ((const uint4*)(z + (size_t)(w3 & 0xffffu) * (R * C)))[j];
        float h0 = rbf_dot(__uint_as_float(w0 & 0xffff0000u), z0, b1j);
        float h1 = rbf_dot(__uint_as_float(w1 & 0xffff0000u), z1, b1j);
        float h2 = rbf_dot(__uint_as_float(w2 & 0xffff0000u), z2, b1j);
        float h3 = rbf_dot(__uint_as_float(w3 & 0xffff0000u), z3, b1j);
        acc += silu_f(h0) + silu_f(h1) + silu_f(h2) + silu_f(h3);
    }
    for (; base < m; ++base) {
        u32 w0 = __shfl(packv, base, 32);
        uint4 z0 = ((const uint4*)(z + (size_t)(w0 & 0xffffu) * (R * C)))[j];
        acc += silu_f(rbf_dot(__uint_as_float(w0 & 0xffff0000u), z0, b1j));
    }
    float v = fmaf((float)deg, b2[j], x[(size_t)n * C + j]);
#pragma unroll
    for (int i = 0; i < C; ++i)
        v = fmaf(__shfl(acc, i, 32), W2s[i * C + j], v);
    out[(size_t)n * C + j] = v;
}

// ---- overflow fix-up ----
__global__ void k_overflow(const int* __restrict__ ovfcnt, const uint4* __restrict__ ovf,
                           const __hip_bfloat16* __restrict__ z,
                           const float* __restrict__ b1, const float* __restrict__ W2,
                           float* __restrict__ out, int N) {
    int novf = ovfcnt[0];
    if (novf > OVF_CAP) novf = OVF_CAP;
    int gt = blockIdx.x * blockDim.x + threadIdx.x;
    int j = gt & 31;
    int g = gt >> 5;
    int ngroups = (gridDim.x * blockDim.x) >> 5;
    for (int q = g; q < novf; q += ngroups) {
        uint4 rec = ovf[q];
        u32 row = rec.x, col = rec.y;
        float dist = __uint_as_float(rec.z);
        uint4 zv = ((const uint4*)(z + (size_t)col * (R * C)))[j];
        float sh = silu_f(rbf_dot(dist, zv, b1[j]));
        float v = 0.f;
#pragma unroll
        for (int i = 0; i < C; ++i)
            v = fmaf(__shfl(sh, i, 32), W2[i * C + j], v);
        atomicAdd(&out[(size_t)row * C + j], v);
    }
}

// rbf for fallback tiers
__device__ __forceinline__ float rbf_lane(float dist, int r) {
    float t = (dist - 0.71428573f * (float)r) * 1.3999999f;
    return 0.3989423f * __expf(-0.5f * t * t);
}

// ---- Tier B kernels (proven fallback) ----
__global__ void k_edge_direct(const int* __restrict__ ei, const float* __restrict__ pos,
                              const float* __restrict__ x, const float* __restrict__ M,
                              const float* __restrict__ b1,
                              float* __restrict__ agg, float* __restrict__ deg,
                              int E, int N) {
    __shared__ float Ms[R * C * C];
    for (int i = threadIdx.x; i < R * C * C; i += blockDim.x) Ms[i] = M[i];
    __syncthreads();
    int gt = blockIdx.x * blockDim.x + threadIdx.x;
    int j = gt & 31;
    int g = gt >> 5;
    int ngroups = (gridDim.x * blockDim.x) >> 5;
    float b1j = b1[j];
    for (int e = g; e < E; e += ngroups) {
        int row = ei[e];
        int col = ei[E + e];
        row = ((unsigned)row < (unsigned)N) ? row : 0;
        col = ((unsigned)col < (unsigned)N) ? col : 0;
        float dx = pos[row * 3 + 0] - pos[col * 3 + 0];
        float dy = pos[row * 3 + 1] - pos[col * 3 + 1];
        float dz = pos[row * 3 + 2] - pos[col * 3 + 2];
        float dist = sqrtf(fmaf(dx, dx, fmaf(dy, dy, dz * dz)) + 1e-12f);
        float my_rbf = rbf_lane(dist, j & 7);
        float xr[C];
#pragma unroll
        for (int c = 0; c < C; ++c) xr[c] = x[(size_t)col * C + c];
        float h = b1j;
#pragma unroll
        for (int r = 0; r < R; ++r) {
            float s = 0.f;
#pragma unroll
            for (int c = 0; c < C; ++c)
                s = fmaf(xr[c], Ms[r * C * C + c * C + j], s);
            h = fmaf(__shfl(my_rbf, r, 32), s, h);
        }
        float sh = h / (1.f + __expf(-h));
        atomicAdd(&agg[(size_t)row * C + j], sh);
        if (j == 0) atomicAdd(&deg[row], 1.f);
    }
}

__global__ void k_final(const float* __restrict__ x, const float* __restrict__ agg,
                        const float* __restrict__ deg, const float* __restrict__ W2,
                        const float* __restrict__ b2, float* __restrict__ out,
                        int N) {
    int t = threadIdx.x;
    int j = t & 31;
    float w2[C];
#pragma unroll
    for (int i = 0; i < C; ++i) w2[i] = W2[i * C + j];
    float b2j = b2[j];
    int g = (blockIdx.x * blockDim.x + t) >> 5;
    int ngroups = (gridDim.x * blockDim.x) >> 5;
    for (int n = g; n < N; n += ngroups) {
        const float* ap = agg + (size_t)n * C;
        float acc = 0.f;
#pragma unroll
        for (int i = 0; i < C; ++i) acc = fmaf(ap[i], w2[i], acc);
        out[(size_t)n * C + j] = x[(size_t)n * C + j] + acc + deg[n] * b2j;
    }
}

// ---- Tier C (no usable ws) ----
__global__ void k_edge_full(const int* __restrict__ ei, const float* __restrict__ pos,
                            const float* __restrict__ x,
                            const float* __restrict__ Wtp, const float* __restrict__ W1,
                            const float* __restrict__ b1,
                            const float* __restrict__ W2, const float* __restrict__ b2,
                            float* __restrict__ out, int E, int N) {
    __shared__ float Ms[R * C * C];
    __shared__ float W2s[C * C];
    for (int idx = threadIdx.x; idx < R * C * C; idx += blockDim.x) {
        int r = idx >> 10, c = (idx >> 5) & 31, jj = idx & 31;
        float acc = 0.f;
#pragma unroll
        for (int o = 0; o < C; ++o)
            acc = fmaf(Wtp[c * R * C + r * C + o], W1[(r * C + o) * C + jj], acc);
        Ms[idx] = acc;
    }
    for (int idx = threadIdx.x; idx < C * C; idx += blockDim.x) W2s[idx] = W2[idx];
    __syncthreads();
    int gt = blockIdx.x * blockDim.x + threadIdx.x;
    int j = gt & 31;
    int g = gt >> 5;
    int ngroups = (gridDim.x * blockDim.x) >> 5;
    float b1j = b1[j];
    float b2j = b2[j];
    for (int e = g; e < E; e += ngroups) {
        int row = ei[e];
        int col = ei[E + e];
        row = ((unsigned)row < (unsigned)N) ? row : 0;
        col = ((unsigned)col < (unsigned)N) ? col : 0;
        float dx = pos[row * 3 + 0] - pos[col * 3 + 0];
        float dy = pos[row * 3 + 1] - pos[col * 3 + 1];
        float dz = pos[row * 3 + 2] - pos[col * 3 + 2];
        float dist = sqrtf(fmaf(dx, dx, fmaf(dy, dy, dz * dz)) + 1e-12f);
        float my_rbf = rbf_lane(dist, j & 7);
        float xr[C];
#pragma unroll
        for (int c = 0; c < C; ++c) xr[c] = x[(size_t)col * C + c];
        float h = b1j;
#pragma unroll
        for (int r = 0; r < R; ++r) {
            float s = 0.f;
#pragma unroll
            for (int c = 0; c < C; ++c)
                s = fmaf(xr[c], Ms[r * C * C + c * C + j], s);
            h = fmaf(__shfl(my_rbf, r, 32), s, h);
        }
        float sh = h / (1.f + __expf(-h));
        float v = b2j;
#pragma unroll
        for (int i = 0; i < C; ++i)
            v = fmaf(__shfl(sh, i, 32), W2s[i * C + j], v);
        atomicAdd(&out[(size_t)row * C + j], v);
    }
}

__global__ void k_add_x(const float* __restrict__ x, float* __restrict__ out, int total) {
    int i = blockIdx.x * blockDim.x + threadIdx.x;
    int stride = gridDim.x * blockDim.x;
    for (; i < total; i += stride) out[i] += x[i];
}

extern "C" void kernel_launch(void* const* d_in, const int* in_sizes, int n_in,
                              void* d_out, int out_size, void* d_ws, size_t ws_size,
                              hipStream_t stream) {
    const float* x   = (const float*)d_in[0];
    const float* pos = (const float*)d_in[1];
    const int*   ei  = (const int*)d_in[2];
    const float* Wtp = (const float*)d_in[3];
    const float* W1  = (const float*)d_in[4];
    const float* b1  = (const float*)d_in[5];
    const float* W2  = (const float*)d_in[6];
    const float* b2  = (const float*)d_in[7];
    int N = in_sizes[0] / C;
    int E = in_sizes[2] / 2;

    char* ws = (char*)d_ws;
    int CAP = E / NBKT + 16384;
    size_t mBytes   = (size_t)R * C * C * sizeof(float);              // 32 KB
    size_t zBytes   = (size_t)N * R * C * sizeof(__hip_bfloat16);     // 25.6 MB
    size_t cntB     = (size_t)N * sizeof(int);                        // 200 KB
    size_t ctrlB    = 64;                                             // ovfcnt + gbcnt[8]
    size_t ovfB     = (size_t)OVF_CAP * 16;                           // 1 MB
    size_t ellB     = (size_t)N * K_ELL * sizeof(u32);                // 6.4 MB
    size_t bktB     = (size_t)NBKT * CAP * sizeof(uint2);             // ~7.5 MB
    size_t aggBytes = (size_t)N * (C + 1) * sizeof(float);            // tier B
    size_t tierANeed = mBytes + zBytes + cntB + ctrlB + ovfB + ellB + bktB;
    bool tierA = (ws_size >= tierANeed) && (N <= 65535);
    bool tierB = !tierA && ws_size >= mBytes + aggBytes;

    if (tierA) {
        size_t off = 0;
        float*          M      = (float*)(ws + off); off += mBytes;
        __hip_bfloat16* z      = (__hip_bfloat16*)(ws + off); off += zBytes;
        int*            cnt    = (int*)(ws + off); off += cntB;
        int*            ctrl   = (int*)(ws + off); off += ctrlB;
        uint4*          ovf    = (uint4*)(ws + off); off += ovfB;
        u32*            ell    = (u32*)(ws + off); off += ellB;
        uint2*          bucket = (uint2*)(ws + off);
        int* ovfcnt = ctrl;       // ctrl[0]
        int* gbcnt  = ctrl + 1;   // ctrl[1..8]

        hipMemsetAsync(cnt, 0, cntB + ctrlB, stream);  // cnt + ovfcnt + gbcnt
        k_prepM<<<(R * C * C + 255) / 256, 256, 0, stream>>>(Wtp, W1, M);
        int RPB8 = (N + NBKT - 1) / NBKT;
        int ZB = (N + NPB - 1) / NPB;
        int SB = (E + 255) / 256;
        k_fused<<<ZB + SB, 256, 0, stream>>>(x, M, z, ei, pos, cnt, ovfcnt, gbcnt,
                                             ovf, bucket, ell, N, E, ZB, RPB8, CAP);
        int s2blocks = ((CAP + 255) / 256) * NBKT;
        k_scatter2<<<s2blocks, 256, 0, stream>>>(bucket, gbcnt, cnt, ovfcnt, ovf,
                                                 ell, CAP);
        int blocks = (int)(((size_t)N * 32 + 255) / 256);
        k_edge_ell<<<blocks, 256, 0, stream>>>(cnt, ell, z, x, b1, W2, b2,
                                               (float*)d_out, N);
        k_overflow<<<16, 256, 0, stream>>>(ovfcnt, ovf, z, b1, W2,
                                           (float*)d_out, N);
    } else if (tierB) {
        float* M   = (float*)ws;
        float* agg = (float*)(ws + mBytes);
        float* deg = agg + (size_t)N * C;
        hipMemsetAsync(agg, 0, aggBytes, stream);
        k_prepM<<<(R * C * C + 255) / 256, 256, 0, stream>>>(Wtp, W1, M);
        k_edge_direct<<<2048, 256, 0, stream>>>(ei, pos, x, M, b1, agg, deg, E, N);
        k_final<<<1024, 256, 0, stream>>>(x, agg, deg, W2, b2, (float*)d_out, N);
    } else {
        hipMemsetAsync(d_out, 0, (size_t)N * C * sizeof(float), stream);
        k_edge_full<<<1024, 256, 0, stream>>>(ei, pos, x, Wtp, W1, b1, W2, b2,
                                              (float*)d_out, E, N);
        k_add_x<<<1024, 256, 0, stream>>>(x, (float*)d_out, N * C);
    }
}

// Round 18
// 142.978 us; speedup vs baseline: 1.1538x; 1.1538x over previous
//
#include <hip/hip_runtime.h>
#include <hip/hip_bf16.h>

#define C 32
#define R 8
#define NPB 32        // nodes per block in k_nodeZ
#define K_ELL 32      // ELL slots per row
#define OVF_CAP 65536

typedef unsigned int u32;
__device__ __forceinline__ float bflo(u32 u) { return __uint_as_float(u << 16); }
__device__ __forceinline__ float bfhi(u32 u) { return __uint_as_float(u & 0xffff0000u); }
__device__ __forceinline__ u32 f2bf_bits(float f) {
    u32 u = __float_as_uint(f);
    u32 lsb = (u >> 16) & 1u;
    return (u + 0x7fffu + lsb) >> 16;
}

// ---- M[r][c][j] = sum_o W_tp[c][r][o] * W1[r*C+o][j]   (f32, 32 KB) ----
__global__ void k_prepM(const float* __restrict__ Wtp, const float* __restrict__ W1,
                        float* __restrict__ M) {
    int idx = blockIdx.x * 256 + threadIdx.x;
    if (idx >= R * C * C) return;
    int r = idx >> 10;
    int c = (idx >> 5) & 31;
    int j = idx & 31;
    float acc = 0.f;
#pragma unroll
    for (int o = 0; o < C; ++o)
        acc = fmaf(Wtp[c * R * C + r * C + o], W1[(r * C + o) * C + j], acc);
    M[idx] = acc;
}

// ---- nodeZ: z[n][j][r] = sum_c x[n][c]*M[r][c][j] (bf16); float4 LDS reads ----
__global__ void k_nodeZ(const float* __restrict__ x, const float* __restrict__ M,
                        __hip_bfloat16* __restrict__ z, int N) {
    __shared__ float4 xs4[NPB * 8];
    int t = threadIdx.x;
    int n0 = blockIdx.x * NPB;
    for (int i = t; i < NPB * 8; i += 256) {
        size_t g4 = (size_t)n0 * 8 + i;
        float4 v = make_float4(0.f, 0.f, 0.f, 0.f);
        if (g4 < (size_t)N * 8) v = ((const float4*)x)[g4];
        xs4[i] = v;
    }
    __syncthreads();
    int r = t & 7, j = t >> 3;
    float m[C];
#pragma unroll
    for (int c = 0; c < C; ++c) m[c] = M[r * C * C + c * C + j];
    int nmax = N - n0; if (nmax > NPB) nmax = NPB;
    for (int nn = 0; nn < nmax; ++nn) {
        const float4* xp = xs4 + nn * 8;
        float acc = 0.f;
#pragma unroll
        for (int c4 = 0; c4 < 8; ++c4) {
            float4 v = xp[c4];
            acc = fmaf(v.x, m[4 * c4 + 0], acc);
            acc = fmaf(v.y, m[4 * c4 + 1], acc);
            acc = fmaf(v.z, m[4 * c4 + 2], acc);
            acc = fmaf(v.w, m[4 * c4 + 3], acc);
        }
        z[(size_t)(n0 + nn) * (R * C) + t] = __float2bfloat16(acc);
    }
}

// ---- scatter: ell[row*32+local] = {col:16 | bf16(dist):16}; grid-stride for ILP ----
__global__ void k_scatter(const int* __restrict__ ei, const float* __restrict__ pos,
                          int* __restrict__ cnt, int* __restrict__ ovfcnt,
                          uint4* __restrict__ ovf, u32* __restrict__ ell,
                          int N, int E) {
    int tid = blockIdx.x * blockDim.x + threadIdx.x;
    int stride = gridDim.x * blockDim.x;
    for (int i = tid; i < E; i += stride) {
        int r = ei[i];
        int c = ei[E + i];
        r = ((unsigned)r < (unsigned)N) ? r : 0;
        c = ((unsigned)c < (unsigned)N) ? c : 0;
        float dx = pos[r * 3 + 0] - pos[c * 3 + 0];
        float dy = pos[r * 3 + 1] - pos[c * 3 + 1];
        float dz = pos[r * 3 + 2] - pos[c * 3 + 2];
        float dist = sqrtf(fmaf(dx, dx, fmaf(dy, dy, dz * dz)) + 1e-12f);
        int local = atomicAdd(&cnt[r], 1);
        if (local < K_ELL) {
            ell[(size_t)r * K_ELL + local] = (u32)c | (f2bf_bits(dist) << 16);
        } else {
            int q = atomicAdd(ovfcnt, 1);
            if (q < OVF_CAP)
                ovf[q] = make_uint4((u32)r, (u32)c, __float_as_uint(dist), 0u);
        }
    }
}

__device__ __forceinline__ float silu_f(float h) {
    return h * __builtin_amdgcn_rcpf(1.f + __expf(-h));
}

// per-lane full-rbf dot: h = b1j + sum_r rbf(d,r)*z_r  — 2 exps, no shuffles.
__device__ __forceinline__ float rbf_dot(float d, uint4 zv, float b1j) {
    const float Einv = 0.36787944f;   // e^-1
    float u = 1.3999999f * d;
    float f = 0.3989423f * __expf(-0.5f * u * u);
    float t = __expf(u - 0.5f);
    float h = fmaf(f, bflo(zv.x), b1j);
    f *= t;            h = fmaf(f, bfhi(zv.x), h);
    t *= Einv; f *= t; h = fmaf(f, bflo(zv.y), h);
    t *= Einv; f *= t; h = fmaf(f, bfhi(zv.y), h);
    t *= Einv; f *= t; h = fmaf(f, bflo(zv.z), h);
    t *= Einv; f *= t; h = fmaf(f, bfhi(zv.z), h);
    t *= Einv; f *= t; h = fmaf(f, bflo(zv.w), h);
    t *= Einv; f *= t; h = fmaf(f, bfhi(zv.w), h);
    return h;
}

// ---- per-row ELL edge kernel: 32 lanes = one row; fused W2/b2 epilogue ----
__global__ void k_edge_ell(const int* __restrict__ cnt, const u32* __restrict__ ell,
                           const __hip_bfloat16* __restrict__ z,
                           const float* __restrict__ x, const float* __restrict__ b1,
                           const float* __restrict__ W2, const float* __restrict__ b2,
                           float* __restrict__ out, int N) {
    __shared__ float W2s[C * C];
    for (int i = threadIdx.x; i < C * C; i += blockDim.x) W2s[i] = W2[i];
    __syncthreads();
    int gt = blockIdx.x * blockDim.x + threadIdx.x;
    int j = gt & 31;
    int n = gt >> 5;
    if (n >= N) return;
    int deg = cnt[n];
    int m = deg < K_ELL ? deg : K_ELL;
    u32 packv = 0u;
    if (j < m) packv = ell[(size_t)n * K_ELL + j];
    float b1j = b1[j];
    float acc = 0.f;
    int base = 0;
    for (; base + 4 <= m; base += 4) {
        u32 w0 = __shfl(packv, base + 0, 32);
        u32 w1 = __shfl(packv, base + 1, 32);
        u32 w2 = __shfl(packv, base + 2, 32);
        u32 w3 = __shfl(packv, base + 3, 32);
        uint4 z0 = ((const uint4*)(z + (size_t)(w0 & 0xffffu) * (R * C)))[j];
        uint4 z1 = ((const uint4*)(z + (size_t)(w1 & 0xffffu) * (R * C)))[j];
        uint4 z2 = ((const uint4*)(z + (size_t)(w2 & 0xffffu) * (R * C)))[j];
        uint4 z3 = ((const uint4*)(z + (size_t)(w3 & 0xffffu) * (R * C)))[j];
        float h0 = rbf_dot(__uint_as_float(w0 & 0xffff0000u), z0, b1j);
        float h1 = rbf_dot(__uint_as_float(w1 & 0xffff0000u), z1, b1j);
        float h2 = rbf_dot(__uint_as_float(w2 & 0xffff0000u), z2, b1j);
        float h3 = rbf_dot(__uint_as_float(w3 & 0xffff0000u), z3, b1j);
        acc += silu_f(h0) + silu_f(h1) + silu_f(h2) + silu_f(h3);
    }
    for (; base < m; ++base) {
        u32 w0 = __shfl(packv, base, 32);
        uint4 z0 = ((const uint4*)(z + (size_t)(w0 & 0xffffu) * (R * C)))[j];
        acc += silu_f(rbf_dot(__uint_as_float(w0 & 0xffff0000u), z0, b1j));
    }
    float v = fmaf((float)deg, b2[j], x[(size_t)n * C + j]);
#pragma unroll
    for (int i = 0; i < C; ++i)
        v = fmaf(__shfl(acc, i, 32), W2s[i * C + j], v);
    out[(size_t)n * C + j] = v;
}

// ---- overflow fix-up ----
__global__ void k_overflow(const int* __restrict__ ovfcnt, const uint4* __restrict__ ovf,
                           const __hip_bfloat16* __restrict__ z,
                           const float* __restrict__ b1, const float* __restrict__ W2,
                           float* __restrict__ out, int N) {
    int novf = ovfcnt[0];
    if (novf > OVF_CAP) novf = OVF_CAP;
    int gt = blockIdx.x * blockDim.x + threadIdx.x;
    int j = gt & 31;
    int g = gt >> 5;
    int ngroups = (gridDim.x * blockDim.x) >> 5;
    for (int q = g; q < novf; q += ngroups) {
        uint4 rec = ovf[q];
        u32 row = rec.x, col = rec.y;
        float dist = __uint_as_float(rec.z);
        uint4 zv = ((const uint4*)(z + (size_t)col * (R * C)))[j];
        float sh = silu_f(rbf_dot(dist, zv, b1[j]));
        float v = 0.f;
#pragma unroll
        for (int i = 0; i < C; ++i)
            v = fmaf(__shfl(sh, i, 32), W2[i * C + j], v);
        atomicAdd(&out[(size_t)row * C + j], v);
    }
}

// rbf for fallback tiers
__device__ __forceinline__ float rbf_lane(float dist, int r) {
    float t = (dist - 0.71428573f * (float)r) * 1.3999999f;
    return 0.3989423f * __expf(-0.5f * t * t);
}

// ---- Tier B kernels (proven fallback) ----
__global__ void k_edge_direct(const int* __restrict__ ei, const float* __restrict__ pos,
                              const float* __restrict__ x, const float* __restrict__ M,
                              const float* __restrict__ b1,
                              float* __restrict__ agg, float* __restrict__ deg,
                              int E, int N) {
    __shared__ float Ms[R * C * C];
    for (int i = threadIdx.x; i < R * C * C; i += blockDim.x) Ms[i] = M[i];
    __syncthreads();
    int gt = blockIdx.x * blockDim.x + threadIdx.x;
    int j = gt & 31;
    int g = gt >> 5;
    int ngroups = (gridDim.x * blockDim.x) >> 5;
    float b1j = b1[j];
    for (int e = g; e < E; e += ngroups) {
        int row = ei[e];
        int col = ei[E + e];
        row = ((unsigned)row < (unsigned)N) ? row : 0;
        col = ((unsigned)col < (unsigned)N) ? col : 0;
        float dx = pos[row * 3 + 0] - pos[col * 3 + 0];
        float dy = pos[row * 3 + 1] - pos[col * 3 + 1];
        float dz = pos[row * 3 + 2] - pos[col * 3 + 2];
        float dist = sqrtf(fmaf(dx, dx, fmaf(dy, dy, dz * dz)) + 1e-12f);
        float my_rbf = rbf_lane(dist, j & 7);
        float xr[C];
#pragma unroll
        for (int c = 0; c < C; ++c) xr[c] = x[(size_t)col * C + c];
        float h = b1j;
#pragma unroll
        for (int r = 0; r < R; ++r) {
            float s = 0.f;
#pragma unroll
            for (int c = 0; c < C; ++c)
                s = fmaf(xr[c], Ms[r * C * C + c * C + j], s);
            h = fmaf(__shfl(my_rbf, r, 32), s, h);
        }
        float sh = h / (1.f + __expf(-h));
        atomicAdd(&agg[(size_t)row * C + j], sh);
        if (j == 0) atomicAdd(&deg[row], 1.f);
    }
}

__global__ void k_final(const float* __restrict__ x, const float* __restrict__ agg,
                        const float* __restrict__ deg, const float* __restrict__ W2,
                        const float* __restrict__ b2, float* __restrict__ out,
                        int N) {
    int t = threadIdx.x;
    int j = t & 31;
    float w2[C];
#pragma unroll
    for (int i = 0; i < C; ++i) w2[i] = W2[i * C + j];
    float b2j = b2[j];
    int g = (blockIdx.x * blockDim.x + t) >> 5;
    int ngroups = (gridDim.x * blockDim.x) >> 5;
    for (int n = g; n < N; n += ngroups) {
        const float* ap = agg + (size_t)n * C;
        float acc = 0.f;
#pragma unroll
        for (int i = 0; i < C; ++i) acc = fmaf(ap[i], w2[i], acc);
        out[(size_t)n * C + j] = x[(size_t)n * C + j] + acc + deg[n] * b2j;
    }
}

// ---- Tier C (no usable ws) ----
__global__ void k_edge_full(const int* __restrict__ ei, const float* __restrict__ pos,
                            const float* __restrict__ x,
                            const float* __restrict__ Wtp, const float* __restrict__ W1,
                            const float* __restrict__ b1,
                            const float* __restrict__ W2, const float* __restrict__ b2,
                            float* __restrict__ out, int E, int N) {
    __shared__ float Ms[R * C * C];
    __shared__ float W2s[C * C];
    for (int idx = threadIdx.x; idx < R * C * C; idx += blockDim.x) {
        int r = idx >> 10, c = (idx >> 5) & 31, jj = idx & 31;
        float acc = 0.f;
#pragma unroll
        for (int o = 0; o < C; ++o)
            acc = fmaf(Wtp[c * R * C + r * C + o], W1[(r * C + o) * C + jj], acc);
        Ms[idx] = acc;
    }
    for (int idx = threadIdx.x; idx < C * C; idx += blockDim.x) W2s[idx] = W2[idx];
    __syncthreads();
    int gt = blockIdx.x * blockDim.x + threadIdx.x;
    int j = gt & 31;
    int g = gt >> 5;
    int ngroups = (gridDim.x * blockDim.x) >> 5;
    float b1j = b1[j];
    float b2j = b2[j];
    for (int e = g; e < E; e += ngroups) {
        int row = ei[e];
        int col = ei[E + e];
        row = ((unsigned)row < (unsigned)N) ? row : 0;
        col = ((unsigned)col < (unsigned)N) ? col : 0;
        float dx = pos[row * 3 + 0] - pos[col * 3 + 0];
        float dy = pos[row * 3 + 1] - pos[col * 3 + 1];
        float dz = pos[row * 3 + 2] - pos[col * 3 + 2];
        float dist = sqrtf(fmaf(dx, dx, fmaf(dy, dy, dz * dz)) + 1e-12f);
        float my_rbf = rbf_lane(dist, j & 7);
        float xr[C];
#pragma unroll
        for (int c = 0; c < C; ++c) xr[c] = x[(size_t)col * C + c];
        float h = b1j;
#pragma unroll
        for (int r = 0; r < R; ++r) {
            float s = 0.f;
#pragma unroll
            for (int c = 0; c < C; ++c)
                s = fmaf(xr[c], Ms[r * C * C + c * C + j], s);
            h = fmaf(__shfl(my_rbf, r, 32), s, h);
        }
        float sh = h / (1.f + __expf(-h));
        float v = b2j;
#pragma unroll
        for (int i = 0; i < C; ++i)
            v = fmaf(__shfl(sh, i, 32), W2s[i * C + j], v);
        atomicAdd(&out[(size_t)row * C + j], v);
    }
}

__global__ void k_add_x(const float* __restrict__ x, float* __restrict__ out, int total) {
    int i = blockIdx.x * blockDim.x + threadIdx.x;
    int stride = gridDim.x * blockDim.x;
    for (; i < total; i += stride) out[i] += x[i];
}

extern "C" void kernel_launch(void* const* d_in, const int* in_sizes, int n_in,
                              void* d_out, int out_size, void* d_ws, size_t ws_size,
                              hipStream_t stream) {
    const float* x   = (const float*)d_in[0];
    const float* pos = (const float*)d_in[1];
    const int*   ei  = (const int*)d_in[2];
    const float* Wtp = (const float*)d_in[3];
    const float* W1  = (const float*)d_in[4];
    const float* b1  = (const float*)d_in[5];
    const float* W2  = (const float*)d_in[6];
    const float* b2  = (const float*)d_in[7];
    int N = in_sizes[0] / C;
    int E = in_sizes[2] / 2;

    char* ws = (char*)d_ws;
    size_t mBytes   = (size_t)R * C * C * sizeof(float);              // 32 KB
    size_t zBytes   = (size_t)N * R * C * sizeof(__hip_bfloat16);     // 25.6 MB
    size_t cntB     = (size_t)N * sizeof(int);                        // 200 KB
    size_t ovfcB    = 64;
    size_t ovfB     = (size_t)OVF_CAP * 16;                           // 1 MB
    size_t ellB     = (size_t)N * K_ELL * sizeof(u32);                // 6.4 MB
    size_t aggBytes = (size_t)N * (C + 1) * sizeof(float);            // tier B
    size_t tierANeed = mBytes + zBytes + cntB + ovfcB + ovfB + ellB;
    bool tierA = (ws_size >= tierANeed) && (N <= 65535);
    bool tierB = !tierA && ws_size >= mBytes + aggBytes;

    if (tierA) {
        size_t off = 0;
        float*          M      = (float*)(ws + off); off += mBytes;
        __hip_bfloat16* z      = (__hip_bfloat16*)(ws + off); off += zBytes;
        int*            cnt    = (int*)(ws + off); off += cntB;
        int*            ovfcnt = (int*)(ws + off); off += ovfcB;
        uint4*          ovf    = (uint4*)(ws + off); off += ovfB;
        u32*            ell    = (u32*)(ws + off);

        hipMemsetAsync(cnt, 0, cntB + ovfcB, stream);  // cnt + ovfcnt adjacent
        k_prepM<<<(R * C * C + 255) / 256, 256, 0, stream>>>(Wtp, W1, M);
        k_scatter<<<1024, 256, 0, stream>>>(ei, pos, cnt, ovfcnt, ovf, ell, N, E);
        k_nodeZ<<<(N + NPB - 1) / NPB, 256, 0, stream>>>(x, M, z, N);
        int blocks = (int)(((size_t)N * 32 + 255) / 256);
        k_edge_ell<<<blocks, 256, 0, stream>>>(cnt, ell, z, x, b1, W2, b2,
                                               (float*)d_out, N);
        k_overflow<<<16, 256, 0, stream>>>(ovfcnt, ovf, z, b1, W2,
                                           (float*)d_out, N);
    } else if (tierB) {
        float* M   = (float*)ws;
        float* agg = (float*)(ws + mBytes);
        float* deg = agg + (size_t)N * C;
        hipMemsetAsync(agg, 0, aggBytes, stream);
        k_prepM<<<(R * C * C + 255) / 256, 256, 0, stream>>>(Wtp, W1, M);
        k_edge_direct<<<2048, 256, 0, stream>>>(ei, pos, x, M, b1, agg, deg, E, N);
        k_final<<<1024, 256, 0, stream>>>(x, agg, deg, W2, b2, (float*)d_out, N);
    } else {
        hipMemsetAsync(d_out, 0, (size_t)N * C * sizeof(float), stream);
        k_edge_full<<<1024, 256, 0, stream>>>(ei, pos, x, Wtp, W1, b1, W2, b2,
                                              (float*)d_out, E, N);
        k_add_x<<<1024, 256, 0, stream>>>(x, (float*)d_out, N * C);
    }
}

// Round 19
// 128.517 us; speedup vs baseline: 1.2836x; 1.1125x over previous
//
#include <hip/hip_runtime.h>
#include <hip/hip_bf16.h>

#define C 32
#define R 8
#define NPB 32        // nodes per block in nodeZ part
#define K_ELL 32      // ELL slots per row
#define OVF_CAP 65536

typedef unsigned int u32;
__device__ __forceinline__ float bflo(u32 u) { return __uint_as_float(u << 16); }
__device__ __forceinline__ float bfhi(u32 u) { return __uint_as_float(u & 0xffff0000u); }
__device__ __forceinline__ u32 f2bf_bits(float f) {
    u32 u = __float_as_uint(f);
    u32 lsb = (u >> 16) & 1u;
    return (u + 0x7fffu + lsb) >> 16;
}

// ---- M[r][c][j] = sum_o W_tp[c][r][o] * W1[r*C+o][j]   (f32, 32 KB) ----
__global__ void k_prepM(const float* __restrict__ Wtp, const float* __restrict__ W1,
                        float* __restrict__ M) {
    int idx = blockIdx.x * 256 + threadIdx.x;
    if (idx >= R * C * C) return;
    int r = idx >> 10;
    int c = (idx >> 5) & 31;
    int j = idx & 31;
    float acc = 0.f;
#pragma unroll
    for (int o = 0; o < C; ++o)
        acc = fmaf(Wtp[c * R * C + r * C + o], W1[(r * C + o) * C + j], acc);
    M[idx] = acc;
}

// ---- fused: blocks [0,ZB): nodeZ (float4 LDS) | blocks [ZB,..): edge scatter ----
// concurrency of the two phases in ONE dispatch is the point (r13 vs r18: -14us)
__global__ void k_fused(const float* __restrict__ x, const float* __restrict__ M,
                        __hip_bfloat16* __restrict__ z,
                        const int* __restrict__ ei, const float* __restrict__ pos,
                        int* __restrict__ cnt, int* __restrict__ ovfcnt,
                        uint4* __restrict__ ovf,
                        u32* __restrict__ ell, int N, int E, int ZB) {
    __shared__ float4 xs4[NPB * 8];
    int t = threadIdx.x;
    if ((int)blockIdx.x < ZB) {
        int n0 = blockIdx.x * NPB;
        for (int i = t; i < NPB * 8; i += 256) {
            size_t g4 = (size_t)n0 * 8 + i;
            float4 v = make_float4(0.f, 0.f, 0.f, 0.f);
            if (g4 < (size_t)N * 8) v = ((const float4*)x)[g4];
            xs4[i] = v;
        }
        __syncthreads();
        int r = t & 7, j = t >> 3;
        float m[C];
#pragma unroll
        for (int c = 0; c < C; ++c) m[c] = M[r * C * C + c * C + j];
        int nmax = N - n0; if (nmax > NPB) nmax = NPB;
        for (int nn = 0; nn < nmax; ++nn) {
            const float4* xp = xs4 + nn * 8;
            float acc = 0.f;
#pragma unroll
            for (int c4 = 0; c4 < 8; ++c4) {
                float4 v = xp[c4];
                acc = fmaf(v.x, m[4 * c4 + 0], acc);
                acc = fmaf(v.y, m[4 * c4 + 1], acc);
                acc = fmaf(v.z, m[4 * c4 + 2], acc);
                acc = fmaf(v.w, m[4 * c4 + 3], acc);
            }
            z[(size_t)(n0 + nn) * (R * C) + t] = __float2bfloat16(acc);
        }
    } else {
        int i = (blockIdx.x - ZB) * 256 + t;
        if (i < E) {
            int r = ei[i];
            int c = ei[E + i];
            r = ((unsigned)r < (unsigned)N) ? r : 0;
            c = ((unsigned)c < (unsigned)N) ? c : 0;
            float dx = pos[r * 3 + 0] - pos[c * 3 + 0];
            float dy = pos[r * 3 + 1] - pos[c * 3 + 1];
            float dz = pos[r * 3 + 2] - pos[c * 3 + 2];
            float dist = sqrtf(fmaf(dx, dx, fmaf(dy, dy, dz * dz)) + 1e-12f);
            int local = atomicAdd(&cnt[r], 1);
            if (local < K_ELL) {
                ell[(size_t)r * K_ELL + local] = (u32)c | (f2bf_bits(dist) << 16);
            } else {
                int q = atomicAdd(ovfcnt, 1);
                if (q < OVF_CAP)
                    ovf[q] = make_uint4((u32)r, (u32)c, __float_as_uint(dist), 0u);
            }
        }
    }
}

__device__ __forceinline__ float silu_f(float h) {
    return h * __builtin_amdgcn_rcpf(1.f + __expf(-h));
}

// per-lane full-rbf dot: h = b1j + sum_r rbf(d,r)*z_r  — 2 exps, no shuffles.
__device__ __forceinline__ float rbf_dot(float d, uint4 zv, float b1j) {
    const float Einv = 0.36787944f;   // e^-1
    float u = 1.3999999f * d;
    float f = 0.3989423f * __expf(-0.5f * u * u);
    float t = __expf(u - 0.5f);
    float h = fmaf(f, bflo(zv.x), b1j);
    f *= t;            h = fmaf(f, bfhi(zv.x), h);
    t *= Einv; f *= t; h = fmaf(f, bflo(zv.y), h);
    t *= Einv; f *= t; h = fmaf(f, bfhi(zv.y), h);
    t *= Einv; f *= t; h = fmaf(f, bflo(zv.z), h);
    t *= Einv; f *= t; h = fmaf(f, bfhi(zv.z), h);
    t *= Einv; f *= t; h = fmaf(f, bflo(zv.w), h);
    t *= Einv; f *= t; h = fmaf(f, bfhi(zv.w), h);
    return h;
}

// ---- per-row ELL edge kernel: 32 lanes = one row; 8-wide ILP; fused epilogue ----
__global__ void k_edge_ell(const int* __restrict__ cnt, const u32* __restrict__ ell,
                           const __hip_bfloat16* __restrict__ z,
                           const float* __restrict__ x, const float* __restrict__ b1,
                           const float* __restrict__ W2, const float* __restrict__ b2,
                           float* __restrict__ out, int N) {
    __shared__ float W2s[C * C];
    for (int i = threadIdx.x; i < C * C; i += blockDim.x) W2s[i] = W2[i];
    __syncthreads();
    int gt = blockIdx.x * blockDim.x + threadIdx.x;
    int j = gt & 31;
    int n = gt >> 5;
    if (n >= N) return;
    int deg = cnt[n];
    int m = deg < K_ELL ? deg : K_ELL;
    u32 packv = 0u;
    if (j < m) packv = ell[(size_t)n * K_ELL + j];
    float b1j = b1[j];
    float acc = 0.f;
    int base = 0;
    for (; base + 8 <= m; base += 8) {
        u32 w0 = __shfl(packv, base + 0, 32);
        u32 w1 = __shfl(packv, base + 1, 32);
        u32 w2 = __shfl(packv, base + 2, 32);
        u32 w3 = __shfl(packv, base + 3, 32);
        u32 w4 = __shfl(packv, base + 4, 32);
        u32 w5 = __shfl(packv, base + 5, 32);
        u32 w6 = __shfl(packv, base + 6, 32);
        u32 w7 = __shfl(packv, base + 7, 32);
        uint4 z0 = ((const uint4*)(z + (size_t)(w0 & 0xffffu) * (R * C)))[j];
        uint4 z1 = ((const uint4*)(z + (size_t)(w1 & 0xffffu) * (R * C)))[j];
        uint4 z2 = ((const uint4*)(z + (size_t)(w2 & 0xffffu) * (R * C)))[j];
        uint4 z3 = ((const uint4*)(z + (size_t)(w3 & 0xffffu) * (R * C)))[j];
        uint4 z4 = ((const uint4*)(z + (size_t)(w4 & 0xffffu) * (R * C)))[j];
        uint4 z5 = ((const uint4*)(z + (size_t)(w5 & 0xffffu) * (R * C)))[j];
        uint4 z6 = ((const uint4*)(z + (size_t)(w6 & 0xffffu) * (R * C)))[j];
        uint4 z7 = ((const uint4*)(z + (size_t)(w7 & 0xffffu) * (R * C)))[j];
        float h0 = rbf_dot(__uint_as_float(w0 & 0xffff0000u), z0, b1j);
        float h1 = rbf_dot(__uint_as_float(w1 & 0xffff0000u), z1, b1j);
        float h2 = rbf_dot(__uint_as_float(w2 & 0xffff0000u), z2, b1j);
        float h3 = rbf_dot(__uint_as_float(w3 & 0xffff0000u), z3, b1j);
        float h4 = rbf_dot(__uint_as_float(w4 & 0xffff0000u), z4, b1j);
        float h5 = rbf_dot(__uint_as_float(w5 & 0xffff0000u), z5, b1j);
        float h6 = rbf_dot(__uint_as_float(w6 & 0xffff0000u), z6, b1j);
        float h7 = rbf_dot(__uint_as_float(w7 & 0xffff0000u), z7, b1j);
        acc += silu_f(h0) + silu_f(h1) + silu_f(h2) + silu_f(h3)
             + silu_f(h4) + silu_f(h5) + silu_f(h6) + silu_f(h7);
    }
    for (; base + 4 <= m; base += 4) {
        u32 w0 = __shfl(packv, base + 0, 32);
        u32 w1 = __shfl(packv, base + 1, 32);
        u32 w2 = __shfl(packv, base + 2, 32);
        u32 w3 = __shfl(packv, base + 3, 32);
        uint4 z0 = ((const uint4*)(z + (size_t)(w0 & 0xffffu) * (R * C)))[j];
        uint4 z1 = ((const uint4*)(z + (size_t)(w1 & 0xffffu) * (R * C)))[j];
        uint4 z2 = ((const uint4*)(z + (size_t)(w2 & 0xffffu) * (R * C)))[j];
        uint4 z3 = ((const uint4*)(z + (size_t)(w3 & 0xffffu) * (R * C)))[j];
        float h0 = rbf_dot(__uint_as_float(w0 & 0xffff0000u), z0, b1j);
        float h1 = rbf_dot(__uint_as_float(w1 & 0xffff0000u), z1, b1j);
        float h2 = rbf_dot(__uint_as_float(w2 & 0xffff0000u), z2, b1j);
        float h3 = rbf_dot(__uint_as_float(w3 & 0xffff0000u), z3, b1j);
        acc += silu_f(h0) + silu_f(h1) + silu_f(h2) + silu_f(h3);
    }
    for (; base < m; ++base) {
        u32 w0 = __shfl(packv, base, 32);
        uint4 z0 = ((const uint4*)(z + (size_t)(w0 & 0xffffu) * (R * C)))[j];
        acc += silu_f(rbf_dot(__uint_as_float(w0 & 0xffff0000u), z0, b1j));
    }
    // out[n][j] = x[n][j] + sum_i acc_i*W2[i][j] + deg*b2[j]   (deg = TRUE degree)
    float v = fmaf((float)deg, b2[j], x[(size_t)n * C + j]);
#pragma unroll
    for (int i = 0; i < C; ++i)
        v = fmaf(__shfl(acc, i, 32), W2s[i * C + j], v);
    out[(size_t)n * C + j] = v;
}

// ---- overflow fix-up: add W2-weighted silu of overflow edges (b2 already counted) ----
__global__ void k_overflow(const int* __restrict__ ovfcnt, const uint4* __restrict__ ovf,
                           const __hip_bfloat16* __restrict__ z,
                           const float* __restrict__ b1, const float* __restrict__ W2,
                           float* __restrict__ out, int N) {
    int novf = ovfcnt[0];
    if (novf > OVF_CAP) novf = OVF_CAP;
    int gt = blockIdx.x * blockDim.x + threadIdx.x;
    int j = gt & 31;
    int g = gt >> 5;
    int ngroups = (gridDim.x * blockDim.x) >> 5;
    for (int q = g; q < novf; q += ngroups) {
        uint4 rec = ovf[q];
        u32 row = rec.x, col = rec.y;
        float dist = __uint_as_float(rec.z);
        uint4 zv = ((const uint4*)(z + (size_t)col * (R * C)))[j];
        float sh = silu_f(rbf_dot(dist, zv, b1[j]));
        float v = 0.f;
#pragma unroll
        for (int i = 0; i < C; ++i)
            v = fmaf(__shfl(sh, i, 32), W2[i * C + j], v);
        atomicAdd(&out[(size_t)row * C + j], v);
    }
}

// rbf for fallback tiers
__device__ __forceinline__ float rbf_lane(float dist, int r) {
    float t = (dist - 0.71428573f * (float)r) * 1.3999999f;
    return 0.3989423f * __expf(-0.5f * t * t);
}

// ---- Tier B kernels (proven fallback) ----
__global__ void k_edge_direct(const int* __restrict__ ei, const float* __restrict__ pos,
                              const float* __restrict__ x, const float* __restrict__ M,
                              const float* __restrict__ b1,
                              float* __restrict__ agg, float* __restrict__ deg,
                              int E, int N) {
    __shared__ float Ms[R * C * C];
    for (int i = threadIdx.x; i < R * C * C; i += blockDim.x) Ms[i] = M[i];
    __syncthreads();
    int gt = blockIdx.x * blockDim.x + threadIdx.x;
    int j = gt & 31;
    int g = gt >> 5;
    int ngroups = (gridDim.x * blockDim.x) >> 5;
    float b1j = b1[j];
    for (int e = g; e < E; e += ngroups) {
        int row = ei[e];
        int col = ei[E + e];
        row = ((unsigned)row < (unsigned)N) ? row : 0;
        col = ((unsigned)col < (unsigned)N) ? col : 0;
        float dx = pos[row * 3 + 0] - pos[col * 3 + 0];
        float dy = pos[row * 3 + 1] - pos[col * 3 + 1];
        float dz = pos[row * 3 + 2] - pos[col * 3 + 2];
        float dist = sqrtf(fmaf(dx, dx, fmaf(dy, dy, dz * dz)) + 1e-12f);
        float my_rbf = rbf_lane(dist, j & 7);
        float xr[C];
#pragma unroll
        for (int c = 0; c < C; ++c) xr[c] = x[(size_t)col * C + c];
        float h = b1j;
#pragma unroll
        for (int r = 0; r < R; ++r) {
            float s = 0.f;
#pragma unroll
            for (int c = 0; c < C; ++c)
                s = fmaf(xr[c], Ms[r * C * C + c * C + j], s);
            h = fmaf(__shfl(my_rbf, r, 32), s, h);
        }
        float sh = h / (1.f + __expf(-h));
        atomicAdd(&agg[(size_t)row * C + j], sh);
        if (j == 0) atomicAdd(&deg[row], 1.f);
    }
}

__global__ void k_final(const float* __restrict__ x, const float* __restrict__ agg,
                        const float* __restrict__ deg, const float* __restrict__ W2,
                        const float* __restrict__ b2, float* __restrict__ out,
                        int N) {
    int t = threadIdx.x;
    int j = t & 31;
    float w2[C];
#pragma unroll
    for (int i = 0; i < C; ++i) w2[i] = W2[i * C + j];
    float b2j = b2[j];
    int g = (blockIdx.x * blockDim.x + t) >> 5;
    int ngroups = (gridDim.x * blockDim.x) >> 5;
    for (int n = g; n < N; n += ngroups) {
        const float* ap = agg + (size_t)n * C;
        float acc = 0.f;
#pragma unroll
        for (int i = 0; i < C; ++i) acc = fmaf(ap[i], w2[i], acc);
        out[(size_t)n * C + j] = x[(size_t)n * C + j] + acc + deg[n] * b2j;
    }
}

// ---- Tier C (no usable ws) ----
__global__ void k_edge_full(const int* __restrict__ ei, const float* __restrict__ pos,
                            const float* __restrict__ x,
                            const float* __restrict__ Wtp, const float* __restrict__ W1,
                            const float* __restrict__ b1,
                            const float* __restrict__ W2, const float* __restrict__ b2,
                            float* __restrict__ out, int E, int N) {
    __shared__ float Ms[R * C * C];
    __shared__ float W2s[C * C];
    for (int idx = threadIdx.x; idx < R * C * C; idx += blockDim.x) {
        int r = idx >> 10, c = (idx >> 5) & 31, jj = idx & 31;
        float acc = 0.f;
#pragma unroll
        for (int o = 0; o < C; ++o)
            acc = fmaf(Wtp[c * R * C + r * C + o], W1[(r * C + o) * C + jj], acc);
        Ms[idx] = acc;
    }
    for (int idx = threadIdx.x; idx < C * C; idx += blockDim.x) W2s[idx] = W2[idx];
    __syncthreads();
    int gt = blockIdx.x * blockDim.x + threadIdx.x;
    int j = gt & 31;
    int g = gt >> 5;
    int ngroups = (gridDim.x * blockDim.x) >> 5;
    float b1j = b1[j];
    float b2j = b2[j];
    for (int e = g; e < E; e += ngroups) {
        int row = ei[e];
        int col = ei[E + e];
        row = ((unsigned)row < (unsigned)N) ? row : 0;
        col = ((unsigned)col < (unsigned)N) ? col : 0;
        float dx = pos[row * 3 + 0] - pos[col * 3 + 0];
        float dy = pos[row * 3 + 1] - pos[col * 3 + 1];
        float dz = pos[row * 3 + 2] - pos[col * 3 + 2];
        float dist = sqrtf(fmaf(dx, dx, fmaf(dy, dy, dz * dz)) + 1e-12f);
        float my_rbf = rbf_lane(dist, j & 7);
        float xr[C];
#pragma unroll
        for (int c = 0; c < C; ++c) xr[c] = x[(size_t)col * C + c];
        float h = b1j;
#pragma unroll
        for (int r = 0; r < R; ++r) {
            float s = 0.f;
#pragma unroll
            for (int c = 0; c < C; ++c)
                s = fmaf(xr[c], Ms[r * C * C + c * C + j], s);
            h = fmaf(__shfl(my_rbf, r, 32), s, h);
        }
        float sh = h / (1.f + __expf(-h));
        float v = b2j;
#pragma unroll
        for (int i = 0; i < C; ++i)
            v = fmaf(__shfl(sh, i, 32), W2s[i * C + j], v);
        atomicAdd(&out[(size_t)row * C + j], v);
    }
}

__global__ void k_add_x(const float* __restrict__ x, float* __restrict__ out, int total) {
    int i = blockIdx.x * blockDim.x + threadIdx.x;
    int stride = gridDim.x * blockDim.x;
    for (; i < total; i += stride) out[i] += x[i];
}

extern "C" void kernel_launch(void* const* d_in, const int* in_sizes, int n_in,
                              void* d_out, int out_size, void* d_ws, size_t ws_size,
                              hipStream_t stream) {
    const float* x   = (const float*)d_in[0];
    const float* pos = (const float*)d_in[1];
    const int*   ei  = (const int*)d_in[2];
    const float* Wtp = (const float*)d_in[3];
    const float* W1  = (const float*)d_in[4];
    const float* b1  = (const float*)d_in[5];
    const float* W2  = (const float*)d_in[6];
    const float* b2  = (const float*)d_in[7];
    int N = in_sizes[0] / C;
    int E = in_sizes[2] / 2;

    char* ws = (char*)d_ws;
    size_t mBytes   = (size_t)R * C * C * sizeof(float);              // 32 KB
    size_t zBytes   = (size_t)N * R * C * sizeof(__hip_bfloat16);     // 25.6 MB
    size_t cntB     = (size_t)N * sizeof(int);                        // 200 KB
    size_t ovfcB    = 64;
    size_t ovfB     = (size_t)OVF_CAP * 16;                           // 1 MB
    size_t ellB     = (size_t)N * K_ELL * sizeof(u32);                // 6.4 MB
    size_t aggBytes = (size_t)N * (C + 1) * sizeof(float);            // tier B
    size_t tierANeed = mBytes + zBytes + cntB + ovfcB + ovfB + ellB;
    bool tierA = (ws_size >= tierANeed) && (N <= 65535);
    bool tierB = !tierA && ws_size >= mBytes + aggBytes;

    if (tierA) {
        size_t off = 0;
        float*          M      = (float*)(ws + off); off += mBytes;
        __hip_bfloat16* z      = (__hip_bfloat16*)(ws + off); off += zBytes;
        int*            cnt    = (int*)(ws + off); off += cntB;
        int*            ovfcnt = (int*)(ws + off); off += ovfcB;
        uint4*          ovf    = (uint4*)(ws + off); off += ovfB;
        u32*            ell    = (u32*)(ws + off);

        hipMemsetAsync(cnt, 0, cntB + ovfcB, stream);  // cnt + ovfcnt adjacent
        k_prepM<<<(R * C * C + 255) / 256, 256, 0, stream>>>(Wtp, W1, M);
        int ZB = (N + NPB - 1) / NPB;
        int SB = (E + 255) / 256;
        k_fused<<<ZB + SB, 256, 0, stream>>>(x, M, z, ei, pos, cnt, ovfcnt, ovf,
                                             ell, N, E, ZB);
        int blocks = (int)(((size_t)N * 32 + 255) / 256);
        k_edge_ell<<<blocks, 256, 0, stream>>>(cnt, ell, z, x, b1, W2, b2,
                                               (float*)d_out, N);
        k_overflow<<<16, 256, 0, stream>>>(ovfcnt, ovf, z, b1, W2,
                                           (float*)d_out, N);
    } else if (tierB) {
        float* M   = (float*)ws;
        float* agg = (float*)(ws + mBytes);
        float* deg = agg + (size_t)N * C;
        hipMemsetAsync(agg, 0, aggBytes, stream);
        k_prepM<<<(R * C * C + 255) / 256, 256, 0, stream>>>(Wtp, W1, M);
        k_edge_direct<<<2048, 256, 0, stream>>>(ei, pos, x, M, b1, agg, deg, E, N);
        k_final<<<1024, 256, 0, stream>>>(x, agg, deg, W2, b2, (float*)d_out, N);
    } else {
        hipMemsetAsync(d_out, 0, (size_t)N * C * sizeof(float), stream);
        k_edge_full<<<1024, 256, 0, stream>>>(ei, pos, x, Wtp, W1, b1, W2, b2,
                                              (float*)d_out, E, N);
        k_add_x<<<1024, 256, 0, stream>>>(x, (float*)d_out, N * C);
    }
}